// Round 10
// baseline (275.753 us; speedup 1.0000x reference)
//
#include <hip/hip_runtime.h>
#include <math.h>

#define N_NODES 16384
#define IN_DIM  512
#define HID_DIM 256
#define OUT_DIM 128
#define MAXDEG  128

typedef float f4v __attribute__((ext_vector_type(4)));
typedef float f32x4 __attribute__((ext_vector_type(4)));
typedef short bf16x8 __attribute__((ext_vector_type(8)));

__device__ __forceinline__ float bf2f(unsigned short u) {
    return __uint_as_float(((unsigned int)u) << 16);
}
__device__ __forceinline__ unsigned short f2bf(float f) {
    unsigned int u = __float_as_uint(f);
    return (unsigned short)((u + 0x7FFFu + ((u >> 16) & 1u)) >> 16);
}

// ---------------------------------------------------------------------------
// W1 [512][256] f32 -> W1T [256][512] bf16 (LDS tile transpose, 32 blocks).
// Proven in round 9.
// ---------------------------------------------------------------------------
__global__ __launch_bounds__(256) void w1t_kernel(
    const float* __restrict__ W1, unsigned short* __restrict__ W1T) {
    __shared__ float tile[64][65];
    const int kb = blockIdx.x * 64, cb = blockIdx.y * 64;
    for (int i = threadIdx.x; i < 64 * 64; i += 256) {
        const int r = i >> 6, c = i & 63;
        tile[r][c] = W1[(size_t)(kb + r) * HID_DIM + cb + c];
    }
    __syncthreads();
    for (int i = threadIdx.x; i < 64 * 64; i += 256) {
        const int c = i >> 6, k = i & 63;
        W1T[(size_t)(cb + c) * IN_DIM + kb + k] = f2bf(tile[k][c]);
    }
}

// ---------------------------------------------------------------------------
// Fused: every 5th block = one 64x64 MFMA tile of h1 = bf16(x @ W1); other
// 4096 blocks scan the 1.07 GB adjacency (4 rows/block, wave/row, NT loads,
// 2-chunk unroll). GEMM branch: K-chunk 64, single-buffered LDS (18.4 KB,
// 144-B row stride -> 2-way bank alias = free). Frag layout (round-8/9
// proven): A row=l&15, k=(l>>4)*8+j; B col=l&15 same k; C/D col=l&15,
// row=(l>>4)*4+r. 18.4 KB LDS keeps scan at the thread-capped 8 blocks/CU.
// ---------------------------------------------------------------------------
__global__ __launch_bounds__(256) void scan_gemm_kernel(
    const float* __restrict__ A,
    int* __restrict__ adj, int* __restrict__ cnt, float* __restrict__ din,
    const float* __restrict__ X, const unsigned short* __restrict__ W1T,
    unsigned short* __restrict__ H1) {
    __shared__ unsigned short xs[64][72];   // 9.2 KB
    __shared__ unsigned short ws[64][72];   // 9.2 KB
    const int bid = blockIdx.x;
    const int tid = threadIdx.x;
    if (bid % 5 == 0) {
        const int g  = bid / 5;            // 0..1023
        const int n0 = (g & 3) * 64;
        const int m0 = (g >> 2) * 64;
        const int wave = tid >> 6, lane = tid & 63;
        const int koff = (lane >> 4) * 8;
        f32x4 acc[4];
        #pragma unroll
        for (int i = 0; i < 4; ++i) acc[i] = {0.f, 0.f, 0.f, 0.f};
        for (int kc = 0; kc < IN_DIM / 64; ++kc) {
            const int k0 = kc * 64;
            #pragma unroll
            for (int j = 0; j < 4; ++j) {          // xs: 64x64 f32 -> bf16
                const int idx = tid + j * 256;
                const int r = idx >> 4, k4 = (idx & 15) * 4;
                const float4 v =
                    *(const float4*)(X + (size_t)(m0 + r) * IN_DIM + k0 + k4);
                ushort4 o;
                o.x = f2bf(v.x); o.y = f2bf(v.y);
                o.z = f2bf(v.z); o.w = f2bf(v.w);
                *(ushort4*)&xs[r][k4] = o;
            }
            #pragma unroll
            for (int j = 0; j < 2; ++j) {          // ws: 64x64 bf16 copy
                const int idx = tid + j * 256;
                const int c = idx >> 3, k8 = (idx & 7) * 8;
                *(uint4*)&ws[c][k8] =
                    *(const uint4*)(W1T + (size_t)(n0 + c) * IN_DIM + k0 + k8);
            }
            __syncthreads();
            #pragma unroll
            for (int ks = 0; ks < 2; ++ks) {
                const bf16x8 af =
                    *(const bf16x8*)&xs[wave * 16 + (lane & 15)][ks * 32 + koff];
                #pragma unroll
                for (int nt = 0; nt < 4; ++nt) {
                    const bf16x8 bfr =
                        *(const bf16x8*)&ws[nt * 16 + (lane & 15)][ks * 32 + koff];
                    acc[nt] = __builtin_amdgcn_mfma_f32_16x16x32_bf16(
                        af, bfr, acc[nt], 0, 0, 0);
                }
            }
            __syncthreads();
        }
        const int orow = m0 + wave * 16 + (lane >> 4) * 4;
        #pragma unroll
        for (int nt = 0; nt < 4; ++nt)
            #pragma unroll
            for (int r = 0; r < 4; ++r)
                H1[(size_t)(orow + r) * HID_DIM + n0 + nt * 16 + (lane & 15)] =
                    f2bf(acc[nt][r]);
        return;
    }
    const int s    = bid - bid / 5 - 1;    // 0..4095
    const int lane = tid & 63;
    const int row  = s * 4 + (tid >> 6);
    const f4v* arow = (const f4v*)(A + (size_t)row * N_NODES);
    const unsigned long long lt = (1ull << lane) - 1ull;
    int base = 0;
    for (int chunk = 0; chunk < N_NODES / 256; chunk += 2) {
        const f4v v0 = __builtin_nontemporal_load(&arow[chunk * 64 + lane]);
        const f4v v1 = __builtin_nontemporal_load(&arow[chunk * 64 + 64 + lane]);
        const float vv[8] = {v0.x, v0.y, v0.z, v0.w, v1.x, v1.y, v1.z, v1.w};
        #pragma unroll
        for (int h = 0; h < 2; ++h) {
            const int c0 = (chunk + h) * 256 + lane * 4;
            #pragma unroll
            for (int i = 0; i < 4; ++i) {
                const bool nz = vv[h * 4 + i] != 0.f;
                const unsigned long long m = __ballot(nz);
                if (nz) {
                    const int p = base + __popcll(m & lt);
                    if (p < MAXDEG) adj[row * MAXDEG + p] = c0 + i;
                }
                base += __popcll(m);
            }
        }
    }
    if (lane == 0) {
        cnt[row] = base < MAXDEG ? base : MAXDEG;
        din[row] = base > 0 ? 1.0f / sqrtf((float)base) : 0.0f;
    }
}

// ---------------------------------------------------------------------------
// agg1: 4 nodes/block (wave per node), bf16 gathers of h1, f32 accumulate,
// ELU + row L2-norm. Writes z1 f32 (output) AND z1b bf16 (layer-2 input).
// ---------------------------------------------------------------------------
__global__ __launch_bounds__(256) void agg1_kernel(
    const unsigned short* __restrict__ h1, const int* __restrict__ adj,
    const int* __restrict__ cnt, const float* __restrict__ din,
    const float* __restrict__ b1, float* __restrict__ z1,
    unsigned short* __restrict__ z1b) {
    __shared__ int   s_adj[4][MAXDEG];
    __shared__ float s_dsc[4][MAXDEG];
    const int wid  = threadIdx.x >> 6;
    const int lane = threadIdx.x & 63;
    const int node = blockIdx.x * 4 + wid;
    const int n    = cnt[node];
    for (int e = lane; e < n; e += 64) {
        const int src = adj[node * MAXDEG + e];
        s_adj[wid][e] = src;
        s_dsc[wid][e] = din[src];
    }
    __syncthreads();
    const int c0 = lane * 4;
    float acc[4] = {};
    #define GATHER(idx_)                                                       \
        do {                                                                   \
            const int ei_ = (idx_);                                            \
            const ushort4 hv_ = *(const ushort4*)(                             \
                h1 + (size_t)s_adj[wid][ei_] * HID_DIM + c0);                  \
            const float w_ = s_dsc[wid][ei_];                                  \
            acc[0] += bf2f(hv_.x) * w_; acc[1] += bf2f(hv_.y) * w_;            \
            acc[2] += bf2f(hv_.z) * w_; acc[3] += bf2f(hv_.w) * w_;            \
        } while (0)
    int e = 0;
    for (; e + 8 <= n; e += 8) {
        #pragma unroll
        for (int uu = 0; uu < 8; ++uu) GATHER(e + uu);
    }
    for (; e < n; ++e) GATHER(e);
    #undef GATHER
    const float dn = din[node];
    float val[4];
    float ss = 0.f;
    #pragma unroll
    for (int u = 0; u < 4; ++u) {
        float v = acc[u] * dn + b1[c0 + u];
        v = v > 0.f ? v : expm1f(v);
        val[u] = v;
        ss += v * v;
    }
    #pragma unroll
    for (int off = 32; off > 0; off >>= 1) ss += __shfl_xor(ss, off, 64);
    const float inv = 1.0f / fmaxf(sqrtf(ss), 1e-12f);
    #pragma unroll
    for (int u = 0; u < 4; ++u) val[u] *= inv;
    *(float4*)(z1 + (size_t)node * HID_DIM + c0) =
        make_float4(val[0], val[1], val[2], val[3]);
    ushort4 ob;
    ob.x = f2bf(val[0]); ob.y = f2bf(val[1]);
    ob.z = f2bf(val[2]); ob.w = f2bf(val[3]);
    *(ushort4*)(z1b + (size_t)node * HID_DIM + c0) = ob;
}

// ---------------------------------------------------------------------------
// gemm2 via MFMA: h2 = bf16(z1b @ W2). Proven in round 8.
// ---------------------------------------------------------------------------
__global__ __launch_bounds__(256) void gemm2_mfma_kernel(
    const unsigned short* __restrict__ Z, const float* __restrict__ W2,
    unsigned short* __restrict__ H2) {
    __shared__ unsigned short W2t[OUT_DIM][HID_DIM + 8];   // 66 KB
    const int tid = threadIdx.x;
    for (int idx = tid; idx < OUT_DIM * HID_DIM / 2; idx += 256) {
        const int n = idx >> 7, kk = (idx & 127) * 2;
        W2t[n][kk]     = f2bf(W2[(size_t)kk * OUT_DIM + n]);
        W2t[n][kk + 1] = f2bf(W2[(size_t)(kk + 1) * OUT_DIM + n]);
    }
    __syncthreads();
    const int wave = tid >> 6, lane = tid & 63;
    const int m0   = blockIdx.x * 64 + wave * 16;
    const int arow = m0 + (lane & 15);
    const int koff = (lane >> 4) * 8;
    bf16x8 afrag[8];
    #pragma unroll
    for (int ks = 0; ks < 8; ++ks)
        afrag[ks] = *(const bf16x8*)(Z + (size_t)arow * HID_DIM + ks * 32 + koff);
    const int orow = m0 + (lane >> 4) * 4;
    #pragma unroll
    for (int nt = 0; nt < 8; ++nt) {
        f32x4 acc = {0.f, 0.f, 0.f, 0.f};
        const unsigned short* wcol = &W2t[nt * 16 + (lane & 15)][koff];
        #pragma unroll
        for (int ks = 0; ks < 8; ++ks) {
            const bf16x8 bfrag = *(const bf16x8*)(wcol + ks * 32);
            acc = __builtin_amdgcn_mfma_f32_16x16x32_bf16(afrag[ks], bfrag, acc,
                                                          0, 0, 0);
        }
        #pragma unroll
        for (int r = 0; r < 4; ++r)
            H2[(size_t)(orow + r) * OUT_DIM + nt * 16 + (lane & 15)] =
                f2bf(acc[r]);
    }
}

// ---------------------------------------------------------------------------
// agg2: 4 nodes/block (wave per node), bf16 gathers of h2, bias + L2-norm.
// ---------------------------------------------------------------------------
__global__ __launch_bounds__(256) void agg2_kernel(
    const unsigned short* __restrict__ h, const int* __restrict__ adj,
    const int* __restrict__ cnt, const float* __restrict__ din,
    const float* __restrict__ bias, float* __restrict__ out) {
    __shared__ int   s_adj[4][MAXDEG];
    __shared__ float s_dsc[4][MAXDEG];
    const int wid  = threadIdx.x >> 6;
    const int lane = threadIdx.x & 63;
    const int node = blockIdx.x * 4 + wid;
    const int n    = cnt[node];
    for (int e = lane; e < n; e += 64) {
        const int src = adj[node * MAXDEG + e];
        s_adj[wid][e] = src;
        s_dsc[wid][e] = din[src];
    }
    __syncthreads();
    const int c0 = lane * 2;
    float acc[2] = {};
    #define GATHER(idx_)                                                       \
        do {                                                                   \
            const int ei_ = (idx_);                                            \
            const ushort2 hv_ = *(const ushort2*)(                             \
                h + (size_t)s_adj[wid][ei_] * OUT_DIM + c0);                   \
            const float w_ = s_dsc[wid][ei_];                                  \
            acc[0] += bf2f(hv_.x) * w_; acc[1] += bf2f(hv_.y) * w_;            \
        } while (0)
    int e = 0;
    for (; e + 8 <= n; e += 8) {
        #pragma unroll
        for (int uu = 0; uu < 8; ++uu) GATHER(e + uu);
    }
    for (; e < n; ++e) GATHER(e);
    #undef GATHER
    const float dn = din[node];
    const float v0 = acc[0] * dn + bias[c0];
    const float v1 = acc[1] * dn + bias[c0 + 1];
    float ss = v0 * v0 + v1 * v1;
    #pragma unroll
    for (int off = 32; off > 0; off >>= 1) ss += __shfl_xor(ss, off, 64);
    const float inv = 1.0f / fmaxf(sqrtf(ss), 1e-12f);
    *(float2*)(out + (size_t)node * OUT_DIM + c0) =
        make_float2(v0 * inv, v1 * inv);
}

// ---------------------------------------------------------------------------
extern "C" void kernel_launch(void* const* d_in, const int* in_sizes, int n_in,
                              void* d_out, int out_size, void* d_ws, size_t ws_size,
                              hipStream_t stream) {
    const float* x  = (const float*)d_in[0];
    const float* A  = (const float*)d_in[1];
    const float* W1 = (const float*)d_in[2];
    const float* b1 = (const float*)d_in[3];
    const float* W2 = (const float*)d_in[4];
    const float* b2 = (const float*)d_in[5];

    float* out = (float*)d_out;
    float* z2  = out;                                   // 16384 x 128
    float* z1  = out + (size_t)N_NODES * OUT_DIM;       // 16384 x 256

    char* p = (char*)d_ws;
    int*   adj = (int*)p;            p += (size_t)N_NODES * MAXDEG * sizeof(int);
    int*   cnt = (int*)p;            p += (size_t)N_NODES * sizeof(int);
    float* din = (float*)p;          p += (size_t)N_NODES * sizeof(float);
    unsigned short* h1 = (unsigned short*)p;
    p += (size_t)N_NODES * HID_DIM * sizeof(unsigned short);
    unsigned short* z1b = (unsigned short*)p;
    p += (size_t)N_NODES * HID_DIM * sizeof(unsigned short);
    unsigned short* h2 = (unsigned short*)p;
    p += (size_t)N_NODES * OUT_DIM * sizeof(unsigned short);
    unsigned short* W1T = (unsigned short*)p;           // 256 x 512 bf16

    // 1) W1T = bf16(W1^T)  (~2 us)
    w1t_kernel<<<dim3(IN_DIM / 64, HID_DIM / 64), 256, 0, stream>>>(W1, W1T);

    // 2) [A-scan || h1 = bf16(x @ W1) via MFMA] fused, bid%5 interleave
    scan_gemm_kernel<<<5120, 256, 0, stream>>>(A, adj, cnt, din, x, W1T, h1);

    // 3) z1 = l2norm(elu(agg(h1*din)*din + b1)) -> f32 out + bf16 ws
    agg1_kernel<<<N_NODES / 4, 256, 0, stream>>>(
        h1, adj, cnt, din, b1, z1, z1b);

    // 4) h2 = bf16(z1b @ W2) via MFMA
    gemm2_mfma_kernel<<<N_NODES / 64, 256, 0, stream>>>(z1b, W2, h2);

    // 5) z2 = l2norm(agg(h2*din)*din + b2) -> f32
    agg2_kernel<<<N_NODES / 4, 256, 0, stream>>>(h2, adj, cnt, din, b2, z2);
}

// Round 11
// 264.174 us; speedup vs baseline: 1.0438x; 1.0438x over previous
//
#include <hip/hip_runtime.h>
#include <math.h>

#define N_NODES 16384
#define IN_DIM  512
#define HID_DIM 256
#define OUT_DIM 128
#define MAXDEG  128

typedef float f4v __attribute__((ext_vector_type(4)));
typedef float f32x4 __attribute__((ext_vector_type(4)));
typedef short bf16x8 __attribute__((ext_vector_type(8)));

__device__ __forceinline__ float bf2f(unsigned short u) {
    return __uint_as_float(((unsigned int)u) << 16);
}
__device__ __forceinline__ unsigned short f2bf(float f) {
    unsigned int u = __float_as_uint(f);
    return (unsigned short)((u + 0x7FFFu + ((u >> 16) & 1u)) >> 16);
}

// ---------------------------------------------------------------------------
// 64x64 f32 GEMM tile (h1 = x @ W1, bf16 out). 256 threads, 4x4 micro-tile,
// K-chunk 16, As transposed [k][m] so fragments are ds_read_b128.
// (R8-proven: f32 VALU GEMM hides under the HBM-bound scan better than the
// MFMA variants tried in R9/R10.)
// ---------------------------------------------------------------------------
__device__ __forceinline__ void gemm_tile_bf16out(
    const float* __restrict__ Amat, const float* __restrict__ B,
    unsigned short* __restrict__ C, int K, int N, int m0, int n0,
    float (*As)[68], float (*Bs)[64]) {
    const int t  = threadIdx.x;
    const int tx = t & 15, ty = t >> 4;
    float acc[4][4] = {};
    for (int kt = 0; kt < K; kt += 16) {
        {
            const int m = t >> 2, k4 = (t & 3) * 4;
            const float4 v = *(const float4*)(Amat + (size_t)(m0 + m) * K + kt + k4);
            As[k4 + 0][m] = v.x; As[k4 + 1][m] = v.y;
            As[k4 + 2][m] = v.z; As[k4 + 3][m] = v.w;
        }
        {
            const int k = t >> 4, c4 = (t & 15) * 4;
            *(float4*)&Bs[k][c4] = *(const float4*)(B + (size_t)(kt + k) * N + n0 + c4);
        }
        __syncthreads();
        #pragma unroll
        for (int k = 0; k < 16; ++k) {
            const float4 a = *(const float4*)&As[k][ty * 4];
            const float4 b = *(const float4*)&Bs[k][tx * 4];
            const float av[4] = {a.x, a.y, a.z, a.w};
            const float bv[4] = {b.x, b.y, b.z, b.w};
            #pragma unroll
            for (int i = 0; i < 4; ++i)
                #pragma unroll
                for (int j = 0; j < 4; ++j)
                    acc[i][j] += av[i] * bv[j];
        }
        __syncthreads();
    }
    #pragma unroll
    for (int i = 0; i < 4; ++i) {
        const size_t off = (size_t)(m0 + ty * 4 + i) * N + n0 + tx * 4;
        ushort4 o;
        o.x = f2bf(acc[i][0]); o.y = f2bf(acc[i][1]);
        o.z = f2bf(acc[i][2]); o.w = f2bf(acc[i][3]);
        *(ushort4*)(C + off) = o;
    }
}

// ---------------------------------------------------------------------------
// Fused: every 5th block = one 64x64 tile of h1 = x @ W1; other 4096 blocks
// scan the 1.07 GB adjacency (4 rows/block, wave/row, nontemporal loads,
// 2-chunk unroll). adj stored as ushort (ids < 16384) -> half the adj bytes.
// ---------------------------------------------------------------------------
__global__ __launch_bounds__(256) void scan_gemm_kernel(
    const float* __restrict__ A,
    unsigned short* __restrict__ adj, int* __restrict__ cnt,
    float* __restrict__ din,
    const float* __restrict__ X, const float* __restrict__ W1,
    unsigned short* __restrict__ H1) {
    __shared__ float As[16][68];
    __shared__ float Bs[16][64];
    const int bid = blockIdx.x;
    if (bid % 5 == 0) {
        const int g  = bid / 5;            // 0..1023
        const int n0 = (g & 3) * 64;
        const int m0 = (g >> 2) * 64;
        gemm_tile_bf16out(X, W1, H1, IN_DIM, HID_DIM, m0, n0, As, Bs);
        return;
    }
    const int s    = bid - bid / 5 - 1;    // 0..4095
    const int lane = threadIdx.x & 63;
    const int row  = s * 4 + (threadIdx.x >> 6);
    const f4v* arow = (const f4v*)(A + (size_t)row * N_NODES);
    const unsigned long long lt = (1ull << lane) - 1ull;
    int base = 0;
    for (int chunk = 0; chunk < N_NODES / 256; chunk += 2) {
        const f4v v0 = __builtin_nontemporal_load(&arow[chunk * 64 + lane]);
        const f4v v1 = __builtin_nontemporal_load(&arow[chunk * 64 + 64 + lane]);
        const float vv[8] = {v0.x, v0.y, v0.z, v0.w, v1.x, v1.y, v1.z, v1.w};
        #pragma unroll
        for (int h = 0; h < 2; ++h) {
            const int c0 = (chunk + h) * 256 + lane * 4;
            #pragma unroll
            for (int i = 0; i < 4; ++i) {
                const bool nz = vv[h * 4 + i] != 0.f;
                const unsigned long long m = __ballot(nz);
                if (nz) {
                    const int p = base + __popcll(m & lt);
                    if (p < MAXDEG)
                        adj[row * MAXDEG + p] = (unsigned short)(c0 + i);
                }
                base += __popcll(m);
            }
        }
    }
    if (lane == 0) {
        cnt[row] = base < MAXDEG ? base : MAXDEG;
        din[row] = base > 0 ? 1.0f / sqrtf((float)base) : 0.0f;
    }
}

// ---------------------------------------------------------------------------
// agg1: 4 nodes/block (wave per node), bf16 gathers of h1, f32 accumulate,
// ELU + row L2-norm. Writes z1 f32 (output) AND z1b bf16 (layer-2 input).
// ---------------------------------------------------------------------------
__global__ __launch_bounds__(256) void agg1_kernel(
    const unsigned short* __restrict__ h1, const unsigned short* __restrict__ adj,
    const int* __restrict__ cnt, const float* __restrict__ din,
    const float* __restrict__ b1, float* __restrict__ z1,
    unsigned short* __restrict__ z1b) {
    __shared__ int   s_adj[4][MAXDEG];
    __shared__ float s_dsc[4][MAXDEG];
    const int wid  = threadIdx.x >> 6;
    const int lane = threadIdx.x & 63;
    const int node = blockIdx.x * 4 + wid;
    const int n    = cnt[node];
    for (int e = lane; e < n; e += 64) {
        const int src = adj[node * MAXDEG + e];
        s_adj[wid][e] = src;
        s_dsc[wid][e] = din[src];
    }
    __syncthreads();
    const int c0 = lane * 4;
    float acc[4] = {};
    #define GATHER(idx_)                                                       \
        do {                                                                   \
            const int ei_ = (idx_);                                            \
            const ushort4 hv_ = *(const ushort4*)(                             \
                h1 + (size_t)s_adj[wid][ei_] * HID_DIM + c0);                  \
            const float w_ = s_dsc[wid][ei_];                                  \
            acc[0] += bf2f(hv_.x) * w_; acc[1] += bf2f(hv_.y) * w_;            \
            acc[2] += bf2f(hv_.z) * w_; acc[3] += bf2f(hv_.w) * w_;            \
        } while (0)
    int e = 0;
    for (; e + 8 <= n; e += 8) {
        #pragma unroll
        for (int uu = 0; uu < 8; ++uu) GATHER(e + uu);
    }
    for (; e < n; ++e) GATHER(e);
    #undef GATHER
    const float dn = din[node];
    float val[4];
    float ss = 0.f;
    #pragma unroll
    for (int u = 0; u < 4; ++u) {
        float v = acc[u] * dn + b1[c0 + u];
        v = v > 0.f ? v : expm1f(v);
        val[u] = v;
        ss += v * v;
    }
    #pragma unroll
    for (int off = 32; off > 0; off >>= 1) ss += __shfl_xor(ss, off, 64);
    const float inv = 1.0f / fmaxf(sqrtf(ss), 1e-12f);
    #pragma unroll
    for (int u = 0; u < 4; ++u) val[u] *= inv;
    *(float4*)(z1 + (size_t)node * HID_DIM + c0) =
        make_float4(val[0], val[1], val[2], val[3]);
    ushort4 ob;
    ob.x = f2bf(val[0]); ob.y = f2bf(val[1]);
    ob.z = f2bf(val[2]); ob.w = f2bf(val[3]);
    *(ushort4*)(z1b + (size_t)node * HID_DIM + c0) = ob;
}

// ---------------------------------------------------------------------------
// gemm2 via MFMA: h2 = bf16(z1b @ W2). R8-proven core; W2t staging now
// coalesced (consecutive lanes read consecutive W2 columns; LDS scatter on
// the write side, rows spread across banks).
// ---------------------------------------------------------------------------
__global__ __launch_bounds__(256) void gemm2_mfma_kernel(
    const unsigned short* __restrict__ Z, const float* __restrict__ W2,
    unsigned short* __restrict__ H2) {
    __shared__ unsigned short W2t[OUT_DIM][HID_DIM + 8];   // 66 KB
    const int tid = threadIdx.x;
    for (int idx = tid; idx < OUT_DIM * HID_DIM / 2; idx += 256) {
        const int k2 = idx >> 7;            // 0..127 -> k pair
        const int n  = idx & 127;           // lanes: consecutive n -> coalesced
        W2t[n][k2 * 2]     = f2bf(W2[(size_t)(k2 * 2) * OUT_DIM + n]);
        W2t[n][k2 * 2 + 1] = f2bf(W2[(size_t)(k2 * 2 + 1) * OUT_DIM + n]);
    }
    __syncthreads();
    const int wave = tid >> 6, lane = tid & 63;
    const int m0   = blockIdx.x * 64 + wave * 16;
    const int arow = m0 + (lane & 15);
    const int koff = (lane >> 4) * 8;
    bf16x8 afrag[8];
    #pragma unroll
    for (int ks = 0; ks < 8; ++ks)
        afrag[ks] = *(const bf16x8*)(Z + (size_t)arow * HID_DIM + ks * 32 + koff);
    const int orow = m0 + (lane >> 4) * 4;
    #pragma unroll
    for (int nt = 0; nt < 8; ++nt) {
        f32x4 acc = {0.f, 0.f, 0.f, 0.f};
        const unsigned short* wcol = &W2t[nt * 16 + (lane & 15)][koff];
        #pragma unroll
        for (int ks = 0; ks < 8; ++ks) {
            const bf16x8 bfrag = *(const bf16x8*)(wcol + ks * 32);
            acc = __builtin_amdgcn_mfma_f32_16x16x32_bf16(afrag[ks], bfrag, acc,
                                                          0, 0, 0);
        }
        #pragma unroll
        for (int r = 0; r < 4; ++r)
            H2[(size_t)(orow + r) * OUT_DIM + nt * 16 + (lane & 15)] =
                f2bf(acc[r]);
    }
}

// ---------------------------------------------------------------------------
// agg2: 4 nodes/block (wave per node), bf16 gathers of h2, bias + L2-norm.
// ---------------------------------------------------------------------------
__global__ __launch_bounds__(256) void agg2_kernel(
    const unsigned short* __restrict__ h, const unsigned short* __restrict__ adj,
    const int* __restrict__ cnt, const float* __restrict__ din,
    const float* __restrict__ bias, float* __restrict__ out) {
    __shared__ int   s_adj[4][MAXDEG];
    __shared__ float s_dsc[4][MAXDEG];
    const int wid  = threadIdx.x >> 6;
    const int lane = threadIdx.x & 63;
    const int node = blockIdx.x * 4 + wid;
    const int n    = cnt[node];
    for (int e = lane; e < n; e += 64) {
        const int src = adj[node * MAXDEG + e];
        s_adj[wid][e] = src;
        s_dsc[wid][e] = din[src];
    }
    __syncthreads();
    const int c0 = lane * 2;
    float acc[2] = {};
    #define GATHER(idx_)                                                       \
        do {                                                                   \
            const int ei_ = (idx_);                                            \
            const ushort2 hv_ = *(const ushort2*)(                             \
                h + (size_t)s_adj[wid][ei_] * OUT_DIM + c0);                   \
            const float w_ = s_dsc[wid][ei_];                                  \
            acc[0] += bf2f(hv_.x) * w_; acc[1] += bf2f(hv_.y) * w_;            \
        } while (0)
    int e = 0;
    for (; e + 8 <= n; e += 8) {
        #pragma unroll
        for (int uu = 0; uu < 8; ++uu) GATHER(e + uu);
    }
    for (; e < n; ++e) GATHER(e);
    #undef GATHER
    const float dn = din[node];
    const float v0 = acc[0] * dn + bias[c0];
    const float v1 = acc[1] * dn + bias[c0 + 1];
    float ss = v0 * v0 + v1 * v1;
    #pragma unroll
    for (int off = 32; off > 0; off >>= 1) ss += __shfl_xor(ss, off, 64);
    const float inv = 1.0f / fmaxf(sqrtf(ss), 1e-12f);
    *(float2*)(out + (size_t)node * OUT_DIM + c0) =
        make_float2(v0 * inv, v1 * inv);
}

// ---------------------------------------------------------------------------
extern "C" void kernel_launch(void* const* d_in, const int* in_sizes, int n_in,
                              void* d_out, int out_size, void* d_ws, size_t ws_size,
                              hipStream_t stream) {
    const float* x  = (const float*)d_in[0];
    const float* A  = (const float*)d_in[1];
    const float* W1 = (const float*)d_in[2];
    const float* b1 = (const float*)d_in[3];
    const float* W2 = (const float*)d_in[4];
    const float* b2 = (const float*)d_in[5];

    float* out = (float*)d_out;
    float* z2  = out;                                   // 16384 x 128
    float* z1  = out + (size_t)N_NODES * OUT_DIM;       // 16384 x 256

    char* p = (char*)d_ws;
    unsigned short* adj = (unsigned short*)p;
    p += (size_t)N_NODES * MAXDEG * sizeof(unsigned short);      // 4.2 MB
    int*   cnt = (int*)p;            p += (size_t)N_NODES * sizeof(int);
    float* din = (float*)p;          p += (size_t)N_NODES * sizeof(float);
    unsigned short* h1 = (unsigned short*)p;
    p += (size_t)N_NODES * HID_DIM * sizeof(unsigned short);
    unsigned short* z1b = (unsigned short*)p;
    p += (size_t)N_NODES * HID_DIM * sizeof(unsigned short);
    unsigned short* h2 = (unsigned short*)p;

    // 1) [A-scan || h1 = bf16(x @ W1)] fused, bid%5 interleave (R8 champion)
    scan_gemm_kernel<<<5120, 256, 0, stream>>>(A, adj, cnt, din, x, W1, h1);

    // 2) z1 = l2norm(elu(agg(h1*din)*din + b1)) -> f32 out + bf16 ws
    agg1_kernel<<<N_NODES / 4, 256, 0, stream>>>(
        h1, adj, cnt, din, b1, z1, z1b);

    // 3) h2 = bf16(z1b @ W2) via MFMA
    gemm2_mfma_kernel<<<N_NODES / 64, 256, 0, stream>>>(z1b, W2, h2);

    // 4) z2 = l2norm(agg(h2*din)*din + b2) -> f32
    agg2_kernel<<<N_NODES / 4, 256, 0, stream>>>(h2, adj, cnt, din, b2, z2);
}